// Round 1
// baseline (931.188 us; speedup 1.0000x reference)
//
#include <hip/hip_runtime.h>
#include <hip/hip_bf16.h>

// Deformable conv, fp32 baseline.
// B=8, C=256, H=W=64, O=256, K=3, stride=1, pad=1, dil=1.
//
// Pipeline:
//   prep_transpose : w_dcn (O,C,9) -> w_t [k][c][o]; w_off (18,C,9) -> w_off_t [c][t][18]
//   offset_conv    : 3x3 conv producing offsets, stored [b][h][w][18] in ws
//   dcn_main       : per block: 16 positions x 256 output channels.
//                    cooperative bilinear sampling into LDS (double buffered),
//                    each thread accumulates 4 o x 4 p in registers.

#define HW 64
#define CCH 256
#define OCH 256
#define BB 8

__global__ void prep_transpose(const float* __restrict__ w_dcn,
                               const float* __restrict__ w_off,
                               float* __restrict__ w_t,
                               float* __restrict__ w_off_t) {
  int i = blockIdx.x * 256 + threadIdx.x;
  if (i < 9 * 256 * 256) {
    int o = i & 255, c = (i >> 8) & 255, k = i >> 16;
    w_t[i] = w_dcn[(o * 256 + c) * 9 + k];
  }
  if (i < 256 * 9 * 18) {
    int oc = i % 18, t = (i / 18) % 9, c = i / (18 * 9);
    w_off_t[i] = w_off[(oc * 256 + c) * 9 + t];
  }
}

// One block per (b, h) row. 4 c-groups of 64 channels; lane = w.
__global__ __launch_bounds__(256) void offset_conv(
    const float* __restrict__ x, const float* __restrict__ w_off_t,
    const float* __restrict__ b_off, float* __restrict__ off_buf) {
  __shared__ float s_red[4][64][18];
  const int tid = threadIdx.x;
  const int g = __builtin_amdgcn_readfirstlane(tid >> 6);  // wave-uniform c-group
  const int w = tid & 63;
  const int h = blockIdx.x & 63;
  const int b = blockIdx.x >> 6;

  float acc[18];
#pragma unroll
  for (int i = 0; i < 18; ++i) acc[i] = 0.f;

  const int c0 = g * 64;
  for (int c = c0; c < c0 + 64; ++c) {
    const float* xb = x + ((b * CCH + c) << 12);
    float xv[9];
#pragma unroll
    for (int ky = 0; ky < 3; ++ky) {
      int y = h + ky - 1;
      bool vy = (y >= 0) && (y < HW);
      const float* row = xb + y * HW;
      xv[ky * 3 + 0] = (vy && w > 0) ? row[w - 1] : 0.f;
      xv[ky * 3 + 1] = vy ? row[w] : 0.f;
      xv[ky * 3 + 2] = (vy && w < HW - 1) ? row[w + 1] : 0.f;
    }
    const float* wr = w_off_t + c * 9 * 18;  // contiguous [t][oc], wave-uniform addr
#pragma unroll
    for (int t = 0; t < 9; ++t)
#pragma unroll
      for (int oc = 0; oc < 18; ++oc) acc[oc] += xv[t] * wr[t * 18 + oc];
  }

#pragma unroll
  for (int oc = 0; oc < 18; ++oc) s_red[g][w][oc] = acc[oc];
  __syncthreads();

  for (int i = tid; i < 64 * 18; i += 256) {
    int p = i / 18, oc = i % 18;
    float v = s_red[0][p][oc] + s_red[1][p][oc] + s_red[2][p][oc] +
              s_red[3][p][oc] + b_off[oc];
    off_buf[((b * HW + h) * HW + p) * 18 + oc] = v;
  }
}

// One block per (b, h, 16-wide w tile). 256 threads.
// Sampling: thread (c_sub=tid>>4, ps=tid&15) produces one bilinear sample.
// Compute: thread (pg=tid>>6, og=tid&63) owns o = og+64j (j=0..3), p = pg*4+pp (pp=0..3).
__global__ __launch_bounds__(256) void dcn_main(
    const float* __restrict__ x, const float* __restrict__ off_buf,
    const float* __restrict__ w_t, float* __restrict__ out) {
  __shared__ int sp_y0[9][16], sp_y1[9][16], sp_x0[9][16], sp_x1[9][16];
  __shared__ float sp_w[9][16][4];
  __shared__ float s_samp[2][16][16];

  const int tid = threadIdx.x;
  const int bid = blockIdx.x;
  const int wt = bid & 3;
  const int h = (bid >> 2) & 63;
  const int b = bid >> 8;
  const int w_base = wt * 16;

  // Phase 0: per-(p,k) sampling parameters.
  if (tid < 144) {
    const int k = tid >> 4, p = tid & 15;
    const int ky = k / 3, kx = k % 3;
    const int w = w_base + p;
    const float offy = off_buf[(((b * HW + h) * HW + w) * 18) + 2 * k];
    const float offx = off_buf[(((b * HW + h) * HW + w) * 18) + 2 * k + 1];
    const float sy = offy + (float)(h - 1 + ky);
    const float sx = offx + (float)(w - 1 + kx);
    const float y0f = floorf(sy), x0f = floorf(sx);
    const float ly = sy - y0f, lx = sx - x0f;
    const int y0 = (int)y0f, x0 = (int)x0f;
    const int y1 = y0 + 1, x1 = x0 + 1;
    const int vy0 = (y0 >= 0) & (y0 < HW), vy1 = (y1 >= 0) & (y1 < HW);
    const int vx0 = (x0 >= 0) & (x0 < HW), vx1 = (x1 >= 0) & (x1 < HW);
    sp_w[k][p][0] = (1.f - ly) * (1.f - lx) * (float)(vy0 & vx0);
    sp_w[k][p][1] = (1.f - ly) * lx * (float)(vy0 & vx1);
    sp_w[k][p][2] = ly * (1.f - lx) * (float)(vy1 & vx0);
    sp_w[k][p][3] = ly * lx * (float)(vy1 & vx1);
    sp_y0[k][p] = min(max(y0, 0), HW - 1) * HW;  // pre-multiplied row offset
    sp_y1[k][p] = min(max(y1, 0), HW - 1) * HW;
    sp_x0[k][p] = min(max(x0, 0), HW - 1);
    sp_x1[k][p] = min(max(x1, 0), HW - 1);
  }
  __syncthreads();

  const int c_sub = tid >> 4, ps = tid & 15;
  const int og = tid & 63;
  const int pg = __builtin_amdgcn_readfirstlane(tid >> 6);
  const int p0 = pg * 4;

  float acc[4][4];
#pragma unroll
  for (int j = 0; j < 4; ++j)
#pragma unroll
    for (int pp = 0; pp < 4; ++pp) acc[j][pp] = 0.f;

  auto do_sample = [&](int kc) -> float {
    const int k = kc >> 4, cb = kc & 15;
    const int c = cb * 16 + c_sub;
    const float* xb = x + ((b * CCH + c) << 12);
    const int y0 = sp_y0[k][ps], y1 = sp_y1[k][ps];
    const int x0 = sp_x0[k][ps], x1 = sp_x1[k][ps];
    const float4 wv = *(const float4*)sp_w[k][ps];
    return wv.x * xb[y0 + x0] + wv.y * xb[y0 + x1] + wv.z * xb[y1 + x0] +
           wv.w * xb[y1 + x1];
  };

  // kc enumerates (k, c-chunk): k = kc>>4, chunk = kc&15 (16 channels each).
  float sv = do_sample(0);
  s_samp[0][c_sub][ps] = sv;
  __syncthreads();

  for (int kc = 0; kc < 144; ++kc) {
    const int cur = kc & 1;
    if (kc + 1 < 144) sv = do_sample(kc + 1);  // issue gathers early (T14)

    const int k = kc >> 4, cb = kc & 15;
    const float* wrow = w_t + ((k * CCH + cb * 16) << 8) + og;  // [k][c][o]
#pragma unroll
    for (int cc = 0; cc < 16; ++cc) {
      const float4 s4 = *(const float4*)&s_samp[cur][cc][p0];  // broadcast read
      const float w0 = wrow[cc * 256];
      const float w1 = wrow[cc * 256 + 64];
      const float w2 = wrow[cc * 256 + 128];
      const float w3 = wrow[cc * 256 + 192];
      acc[0][0] += s4.x * w0; acc[0][1] += s4.y * w0;
      acc[0][2] += s4.z * w0; acc[0][3] += s4.w * w0;
      acc[1][0] += s4.x * w1; acc[1][1] += s4.y * w1;
      acc[1][2] += s4.z * w1; acc[1][3] += s4.w * w1;
      acc[2][0] += s4.x * w2; acc[2][1] += s4.y * w2;
      acc[2][2] += s4.z * w2; acc[2][3] += s4.w * w2;
      acc[3][0] += s4.x * w3; acc[3][1] += s4.y * w3;
      acc[3][2] += s4.z * w3; acc[3][3] += s4.w * w3;
    }
    if (kc + 1 < 144) s_samp[cur ^ 1][c_sub][ps] = sv;  // write-late
    __syncthreads();
  }

#pragma unroll
  for (int j = 0; j < 4; ++j) {
    const int o = og + 64 * j;
    float4 v;
    v.x = acc[j][0]; v.y = acc[j][1]; v.z = acc[j][2]; v.w = acc[j][3];
    *(float4*)&out[(((b * OCH + o) * HW + h) * HW) + w_base + p0] = v;
  }
}

extern "C" void kernel_launch(void* const* d_in, const int* in_sizes, int n_in,
                              void* d_out, int out_size, void* d_ws,
                              size_t ws_size, hipStream_t stream) {
  const float* x = (const float*)d_in[0];
  const float* w_off = (const float*)d_in[1];
  const float* b_off = (const float*)d_in[2];
  const float* w_dcn = (const float*)d_in[3];
  float* out = (float*)d_out;

  float* ws = (float*)d_ws;
  float* off_buf = ws;                   // B*H*W*18   = 589824 floats
  float* w_t = ws + 589824;              // 9*C*O      = 589824 floats
  float* w_off_t = ws + 2 * 589824;      // C*9*18     = 41472 floats

  prep_transpose<<<2304, 256, 0, stream>>>(w_dcn, w_off, w_t, w_off_t);
  offset_conv<<<BB * HW, 256, 0, stream>>>(x, w_off_t, b_off, off_buf);
  dcn_main<<<BB * HW * (HW / 16), 256, 0, stream>>>(x, off_buf, w_t, out);
}

// Round 2
// 290.096 us; speedup vs baseline: 3.2099x; 3.2099x over previous
//
#include <hip/hip_runtime.h>
#include <hip/hip_bf16.h>

// Deformable conv via implicit GEMM on MFMA.
// B=8, C=256, H=W=64, O=256, K=3.
// Stages: prep (weight transposes) ; xpose (x->NHWC) ; offset_conv ;
//         sampler (bilinear -> S[M=32768][K=2304] bf16) ;
//         dcn_gemm (C = S * W2^T via mfma_f32_16x16x32_bf16).

#define HW 64
#define CCH 256
#define OCH 256
#define BB 8
#define KDIM 2304  // 9 * 256, order k*256 + c

typedef __attribute__((ext_vector_type(8))) short bf16x8;
typedef __attribute__((ext_vector_type(4))) float f32x4;
typedef __attribute__((ext_vector_type(4))) unsigned short u16x4;

static __device__ inline unsigned short f2bf(float f) {
  unsigned u = __builtin_bit_cast(unsigned, f);
  u += 0x7FFFu + ((u >> 16) & 1u);  // RNE
  return (unsigned short)(u >> 16);
}

#define GLL16(gsrc, ldst)                                                      \
  __builtin_amdgcn_global_load_lds(                                           \
      (const __attribute__((address_space(1))) void*)(gsrc),                  \
      (__attribute__((address_space(3))) void*)(ldst), 16, 0, 0)

// ---------------- prep: weight transposes ----------------
// W2[o][kk*256+c] = bf16(w_dcn[o][c][kk])   (GEMM B^T operand, K-major rows)
// w_off_t[c][t][18] for offset_conv (as in R1)
__global__ __launch_bounds__(256) void prep(const float* __restrict__ w_dcn,
                                            const float* __restrict__ w_off,
                                            unsigned short* __restrict__ W2,
                                            float* __restrict__ w_off_t) {
  int i = blockIdx.x * 256 + threadIdx.x;
  if (i < 9 * 256 * 256) {
    int o = i / KDIM;
    int r = i - o * KDIM;
    int kk = r >> 8, c = r & 255;
    W2[i] = f2bf(w_dcn[((o << 8) + c) * 9 + kk]);
  }
  if (i < 256 * 9 * 18) {
    int oc = i % 18, t = (i / 18) % 9, c = i / (18 * 9);
    w_off_t[i] = w_off[(oc * 256 + c) * 9 + t];
  }
}

// ---------------- xpose: NCHW -> NHWC ----------------
__global__ __launch_bounds__(256) void xpose(const float* __restrict__ x,
                                             float* __restrict__ xT) {
  __shared__ float t[64][65];
  const int tid = threadIdx.x;
  const int bid = blockIdx.x;
  const int ct = bid & 3;          // 64-channel tile
  const int pt = (bid >> 2) & 63;  // 64-position tile
  const int b = bid >> 8;
#pragma unroll
  for (int i = 0; i < 16; ++i) {
    int cl = i * 4 + (tid >> 6);
    int p = tid & 63;
    t[cl][p] = x[(((b << 8) + ct * 64 + cl) << 12) + pt * 64 + p];
  }
  __syncthreads();
#pragma unroll
  for (int i = 0; i < 16; ++i) {
    int pl = i * 4 + (tid >> 6);
    int c = tid & 63;
    xT[(size_t)(((b << 12) + pt * 64 + pl) << 8) + ct * 64 + c] = t[c][pl];
  }
}

// ---------------- offset_conv (unchanged from R1, validated) ----------------
__global__ __launch_bounds__(256) void offset_conv(
    const float* __restrict__ x, const float* __restrict__ w_off_t,
    const float* __restrict__ b_off, float* __restrict__ off_buf) {
  __shared__ float s_red[4][64][18];
  const int tid = threadIdx.x;
  const int g = __builtin_amdgcn_readfirstlane(tid >> 6);
  const int w = tid & 63;
  const int h = blockIdx.x & 63;
  const int b = blockIdx.x >> 6;

  float acc[18];
#pragma unroll
  for (int i = 0; i < 18; ++i) acc[i] = 0.f;

  const int c0 = g * 64;
  for (int c = c0; c < c0 + 64; ++c) {
    const float* xb = x + ((b * CCH + c) << 12);
    float xv[9];
#pragma unroll
    for (int ky = 0; ky < 3; ++ky) {
      int y = h + ky - 1;
      bool vy = (y >= 0) && (y < HW);
      const float* row = xb + y * HW;
      xv[ky * 3 + 0] = (vy && w > 0) ? row[w - 1] : 0.f;
      xv[ky * 3 + 1] = vy ? row[w] : 0.f;
      xv[ky * 3 + 2] = (vy && w < HW - 1) ? row[w + 1] : 0.f;
    }
    const float* wr = w_off_t + c * 9 * 18;
#pragma unroll
    for (int t = 0; t < 9; ++t)
#pragma unroll
      for (int oc = 0; oc < 18; ++oc) acc[oc] += xv[t] * wr[t * 18 + oc];
  }

#pragma unroll
  for (int oc = 0; oc < 18; ++oc) s_red[g][w][oc] = acc[oc];
  __syncthreads();

  for (int i = tid; i < 64 * 18; i += 256) {
    int p = i / 18, oc = i % 18;
    float v = s_red[0][p][oc] + s_red[1][p][oc] + s_red[2][p][oc] +
              s_red[3][p][oc] + b_off[oc];
    off_buf[((b * HW + h) * HW + p) * 18 + oc] = v;
  }
}

// ---------------- sampler: bilinear -> S bf16 ----------------
// Block = (b,h) row; 8 waves; wave task = one (w,k): all 256 channels.
__global__ __launch_bounds__(512) void sampler(const float* __restrict__ xT,
                                               const float* __restrict__ off_buf,
                                               unsigned short* __restrict__ S) {
  const int tid = threadIdx.x;
  const int lane = tid & 63;
  const int ww = __builtin_amdgcn_readfirstlane(tid >> 6);
  const int h = blockIdx.x & 63;
  const int b = blockIdx.x >> 6;
  const int rowbase = (b << 12) + (h << 6);
  const float* xb = xT + ((size_t)b << 20);

  for (int t = ww; t < 576; t += 8) {
    const int w = t / 9, k = t - w * 9;
    const int ky = k / 3, kx = k - ky * 3;
    const float offy = off_buf[(rowbase + w) * 18 + 2 * k];
    const float offx = off_buf[(rowbase + w) * 18 + 2 * k + 1];
    const float sy = offy + (float)(h - 1 + ky);
    const float sx = offx + (float)(w - 1 + kx);
    const float y0f = floorf(sy), x0f = floorf(sx);
    const float ly = sy - y0f, lx = sx - x0f;
    const int y0 = (int)y0f, x0 = (int)x0f;
    const int y1 = y0 + 1, x1 = x0 + 1;
    const float vy0 = (y0 >= 0 && y0 < HW) ? 1.f : 0.f;
    const float vy1 = (y1 >= 0 && y1 < HW) ? 1.f : 0.f;
    const float vx0 = (x0 >= 0 && x0 < HW) ? 1.f : 0.f;
    const float vx1 = (x1 >= 0 && x1 < HW) ? 1.f : 0.f;
    const float w00 = (1.f - ly) * (1.f - lx) * vy0 * vx0;
    const float w01 = (1.f - ly) * lx * vy0 * vx1;
    const float w10 = ly * (1.f - lx) * vy1 * vx0;
    const float w11 = ly * lx * vy1 * vx1;
    const int y0c = min(max(y0, 0), HW - 1), y1c = min(max(y1, 0), HW - 1);
    const int x0c = min(max(x0, 0), HW - 1), x1c = min(max(x1, 0), HW - 1);

    const float4 a = *(const float4*)(xb + ((((y0c << 6) + x0c) << 8) + lane * 4));
    const float4 bv = *(const float4*)(xb + ((((y0c << 6) + x1c) << 8) + lane * 4));
    const float4 c = *(const float4*)(xb + ((((y1c << 6) + x0c) << 8) + lane * 4));
    const float4 d = *(const float4*)(xb + ((((y1c << 6) + x1c) << 8) + lane * 4));

    u16x4 o;
    o[0] = f2bf(w00 * a.x + w01 * bv.x + w10 * c.x + w11 * d.x);
    o[1] = f2bf(w00 * a.y + w01 * bv.y + w10 * c.y + w11 * d.y);
    o[2] = f2bf(w00 * a.z + w01 * bv.z + w10 * c.z + w11 * d.z);
    o[3] = f2bf(w00 * a.w + w01 * bv.w + w10 * c.w + w11 * d.w);
    *(u16x4*)(S + (size_t)(rowbase + w) * KDIM + k * 256 + lane * 4) = o;
  }
}

// ---------------- dcn_gemm: C[32768x256] = S * W2^T ----------------
// BM=128, BN=256(all), BK=32. 8 waves (2M x 4N), wave tile 64x64.
// Tiles in LDS as [row][32k] bf16, 16B-chunk XOR swizzle: chunk ^= (row>>1)&3.
__global__ __launch_bounds__(512) void dcn_gemm(
    const unsigned short* __restrict__ S, const unsigned short* __restrict__ W2,
    float* __restrict__ out) {
  __shared__ short ldsA[2][128 * 32];
  __shared__ short ldsB[2][256 * 32];
  const int tid = threadIdx.x;
  const int m0 = blockIdx.x * 128;

  // staging sources (pre-swizzled so linear global_load_lds lands swizzled)
  const int rowA = tid >> 2;
  const int scA = (tid & 3) ^ ((rowA >> 1) & 3);
  const unsigned short* srcA = S + (size_t)(m0 + rowA) * KDIM + scA * 8;
  const unsigned short* srcB0 = W2 + (size_t)rowA * KDIM + scA * 8;
  const int rowB1 = 128 + rowA;
  const int scB1 = (tid & 3) ^ ((rowB1 >> 1) & 3);
  const unsigned short* srcB1 = W2 + (size_t)rowB1 * KDIM + scB1 * 8;

  const int lane = tid & 63;
  const int l15 = lane & 15, l4 = lane >> 4;
  const int wid = __builtin_amdgcn_readfirstlane(tid >> 6);
  const int wm = wid & 1, wn = wid >> 1;

  int offA[4], offB[4];
#pragma unroll
  for (int f = 0; f < 4; ++f) {
    int rA = wm * 64 + f * 16 + l15;
    offA[f] = rA * 32 + ((l4 ^ ((rA >> 1) & 3)) << 3);
    int rB = wn * 64 + f * 16 + l15;
    offB[f] = rB * 32 + ((l4 ^ ((rB >> 1) & 3)) << 3);
  }

  const f32x4 z = {0.f, 0.f, 0.f, 0.f};
  f32x4 acc[4][4];
#pragma unroll
  for (int i = 0; i < 4; ++i)
#pragma unroll
    for (int j = 0; j < 4; ++j) acc[i][j] = z;

  // prologue: stage k-tile 0
  GLL16(srcA, &ldsA[0][tid * 8]);
  GLL16(srcB0, &ldsB[0][tid * 8]);
  GLL16(srcB1, &ldsB[0][(512 + tid) * 8]);
  __syncthreads();

  for (int t = 0; t < 72; ++t) {
    const int buf = t & 1;
    if (t < 71) {
      const int k0 = (t + 1) * 32;
      GLL16(srcA + k0, &ldsA[buf ^ 1][tid * 8]);
      GLL16(srcB0 + k0, &ldsB[buf ^ 1][tid * 8]);
      GLL16(srcB1 + k0, &ldsB[buf ^ 1][(512 + tid) * 8]);
    }
    bf16x8 af[4], bfr[4];
#pragma unroll
    for (int f = 0; f < 4; ++f) af[f] = *(const bf16x8*)&ldsA[buf][offA[f]];
#pragma unroll
    for (int f = 0; f < 4; ++f) bfr[f] = *(const bf16x8*)&ldsB[buf][offB[f]];
#pragma unroll
    for (int i = 0; i < 4; ++i)
#pragma unroll
      for (int j = 0; j < 4; ++j)
        acc[i][j] = __builtin_amdgcn_mfma_f32_16x16x32_bf16(af[i], bfr[j],
                                                            acc[i][j], 0, 0, 0);
    __syncthreads();
  }

  // epilogue: D[(l>>4)*4+r][l&15]; rows are positions (contiguous in out)
#pragma unroll
  for (int i = 0; i < 4; ++i) {
    const int m = m0 + wm * 64 + i * 16 + l4 * 4;
    const int bb = m >> 12;
    const int pos = m & 4095;
#pragma unroll
    for (int j = 0; j < 4; ++j) {
      const int o = wn * 64 + j * 16 + l15;
      *(f32x4*)(out + (((size_t)bb * OCH + o) << 12) + pos) = acc[i][j];
    }
  }
}

extern "C" void kernel_launch(void* const* d_in, const int* in_sizes, int n_in,
                              void* d_out, int out_size, void* d_ws,
                              size_t ws_size, hipStream_t stream) {
  const float* x = (const float*)d_in[0];
  const float* w_off = (const float*)d_in[1];
  const float* b_off = (const float*)d_in[2];
  const float* w_dcn = (const float*)d_in[3];
  float* out = (float*)d_out;

  char* ws = (char*)d_ws;
  float* off_buf = (float*)(ws);                       // 2,359,296 B
  float* w_off_t = (float*)(ws + 2359296);             //   165,888 B
  unsigned short* W2 = (unsigned short*)(ws + 2525184);      // 1,179,648 B
  float* xT = (float*)(ws + 3704832);                  // 33,554,432 B
  unsigned short* S = (unsigned short*)(ws + 37259264);      // 150,994,944 B
  // total ~188.3 MB of ws

  prep<<<2304, 256, 0, stream>>>(w_dcn, w_off, W2, w_off_t);
  xpose<<<2048, 256, 0, stream>>>(x, xT);
  offset_conv<<<BB * HW, 256, 0, stream>>>(x, w_off_t, b_off, off_buf);
  sampler<<<BB * HW, 512, 0, stream>>>(xT, off_buf, S);
  dcn_gemm<<<256, 512, 0, stream>>>(S, W2, out);
}

// Round 3
// 171.514 us; speedup vs baseline: 5.4292x; 1.6914x over previous
//
#include <hip/hip_runtime.h>
#include <hip/hip_bf16.h>

// Deformable conv via implicit GEMM on MFMA — offset conv is now ALSO a GEMM.
// B=8, C=256, H=W=64, O=256, K=3.
// Stages: prep (weights->bf16, zero page) ; xpose (x -> bf16 NHWC) ;
//         offset_gemm (M=32768,N=32(18),K=2304 fixed-grid im2col) ;
//         sampler (bilinear -> S[32768][2304] bf16) ;
//         dcn_gemm (out = S * W2^T, mfma 16x16x32 bf16).

#define HW 64
#define CCH 256
#define OCH 256
#define BB 8
#define KDIM 2304  // 9 * 256, order kk*256 + c

typedef __attribute__((ext_vector_type(8))) short bf16x8;
typedef __attribute__((ext_vector_type(4))) float f32x4;
typedef __attribute__((ext_vector_type(4))) unsigned short u16x4;

static __device__ inline unsigned short f2bf(float f) {
  unsigned u = __builtin_bit_cast(unsigned, f);
  u += 0x7FFFu + ((u >> 16) & 1u);  // RNE
  return (unsigned short)(u >> 16);
}
static __device__ inline float bf2f(unsigned short s) {
  return __builtin_bit_cast(float, (unsigned)s << 16);
}

#define GLL16(gsrc, ldst)                                                      \
  __builtin_amdgcn_global_load_lds(                                           \
      (const __attribute__((address_space(1))) void*)(gsrc),                  \
      (__attribute__((address_space(3))) void*)(ldst), 16, 0, 0)

// ---------------- prep ----------------
// W2[o][kk*256+c]  = bf16(w_dcn[o][c][kk])      (main GEMM B^T)
// Wop[n][kk*256+c] = bf16(w_off[n][c][kk]) n<18, else 0  (offset GEMM B^T)
// zp: 512 bf16 zeros (border page)
__global__ __launch_bounds__(256) void prep(const float* __restrict__ w_dcn,
                                            const float* __restrict__ w_off,
                                            unsigned short* __restrict__ W2,
                                            unsigned short* __restrict__ Wop,
                                            unsigned short* __restrict__ zp) {
  int i = blockIdx.x * 256 + threadIdx.x;
  if (i < 9 * 256 * 256) {
    int o = i / KDIM;
    int r = i - o * KDIM;
    int kk = r >> 8, c = r & 255;
    W2[i] = f2bf(w_dcn[((o << 8) + c) * 9 + kk]);
  }
  if (i < 32 * KDIM) {
    int n = i / KDIM;
    int r = i - n * KDIM;
    int kk = r >> 8, c = r & 255;
    Wop[i] = (n < 18) ? f2bf(w_off[((n << 8) + c) * 9 + kk]) : (unsigned short)0;
  }
  if (i < 512) zp[i] = 0;
}

// ---------------- xpose: NCHW f32 -> NHWC bf16 ----------------
__global__ __launch_bounds__(256) void xpose(const float* __restrict__ x,
                                             unsigned short* __restrict__ xTbf) {
  __shared__ float t[64][65];
  const int tid = threadIdx.x;
  const int bid = blockIdx.x;
  const int ct = bid & 3;          // 64-channel tile
  const int pt = (bid >> 2) & 63;  // 64-position tile
  const int b = bid >> 8;
#pragma unroll
  for (int i = 0; i < 16; ++i) {
    int cl = i * 4 + (tid >> 6);
    int p = tid & 63;
    t[cl][p] = x[(((b << 8) + ct * 64 + cl) << 12) + pt * 64 + p];
  }
  __syncthreads();
#pragma unroll
  for (int i = 0; i < 4; ++i) {
    int pl = i * 16 + (tid >> 4);
    int c4 = (tid & 15) * 4;
    u16x4 v;
    v[0] = f2bf(t[c4][pl]);
    v[1] = f2bf(t[c4 + 1][pl]);
    v[2] = f2bf(t[c4 + 2][pl]);
    v[3] = f2bf(t[c4 + 3][pl]);
    *(u16x4*)(xTbf + (((size_t)((b << 12) + pt * 64 + pl)) << 8) + ct * 64 + c4) = v;
  }
}

// ---------------- offset_gemm ----------------
// off[m][oc] = sum_k A[m][k] * Wop[oc][k],  A = fixed-grid im2col of xTbf.
// 256 threads (4 waves). BM=128, BN=32 (18 used), BK=32, double-buffered.
__global__ __launch_bounds__(256) void offset_gemm(
    const unsigned short* __restrict__ xTbf, const unsigned short* __restrict__ Wop,
    const unsigned short* __restrict__ zp, const float* __restrict__ b_off,
    float* __restrict__ off_buf) {
  __shared__ short ldsA[2][128 * 32];
  __shared__ short ldsB[2][32 * 32];
  const int tid = threadIdx.x;
  const int lane = tid & 63;
  const int wid = __builtin_amdgcn_readfirstlane(tid >> 6);
  const int m0 = blockIdx.x * 128;
  const int b = m0 >> 12;  // uniform: 32 blocks per image
  const unsigned short* xb = xTbf + ((size_t)b << 20);

  // A staging: GLL g in {0,1}: row rA = wid*32 + g*16 + (lane>>2), chunk cc = lane&3.
  int hA[2], wA[2], scA[2];
#pragma unroll
  for (int g = 0; g < 2; ++g) {
    int r = wid * 32 + g * 16 + (lane >> 2);
    int pos = (m0 & 4095) + r;
    hA[g] = pos >> 6;
    wA[g] = pos & 63;
    scA[g] = ((lane & 3) ^ ((r >> 1) & 3)) * 8;  // pre-swizzled source chunk
  }
  // B staging: waves 0,1: row rB = wid*16 + (lane>>2), chunk lane&3.
  const int rB = wid * 16 + (lane >> 2);
  const unsigned short* srcB =
      Wop + (size_t)rB * KDIM + ((lane & 3) ^ ((rB >> 1) & 3)) * 8;

  // fragment read offsets (swizzled)
  const int l15 = lane & 15, l4 = lane >> 4;
  int offA[2], offB[2];
#pragma unroll
  for (int f = 0; f < 2; ++f) {
    int rA = wid * 32 + f * 16 + l15;
    offA[f] = rA * 32 + ((l4 ^ ((rA >> 1) & 3)) << 3);
    int rb = f * 16 + l15;
    offB[f] = rb * 32 + ((l4 ^ ((rb >> 1) & 3)) << 3);
  }

  const f32x4 z = {0.f, 0.f, 0.f, 0.f};
  f32x4 acc[2][2];
#pragma unroll
  for (int i = 0; i < 2; ++i)
#pragma unroll
    for (int j = 0; j < 2; ++j) acc[i][j] = z;

  auto stage = [&](int buf, int t) {
    const int kk = t >> 3;
    const int c0 = (t & 7) * 32;
    const int dy = kk / 3 - 1, dx = kk - (kk / 3) * 3 - 1;
#pragma unroll
    for (int g = 0; g < 2; ++g) {
      const int y = hA[g] + dy, xx = wA[g] + dx;
      const bool valid = ((unsigned)y < 64u) && ((unsigned)xx < 64u);
      const unsigned short* src =
          valid ? xb + ((((y << 6) + xx) << 8) + c0 + scA[g]) : zp + scA[g];
      GLL16(src, &ldsA[buf][((wid * 2 + g) * 64 + lane) * 8]);
    }
    if (wid < 2) GLL16(srcB + t * 32, &ldsB[buf][(wid * 64 + lane) * 8]);
  };

  stage(0, 0);
  __syncthreads();

  for (int t = 0; t < 72; ++t) {
    const int buf = t & 1;
    if (t < 71) stage(buf ^ 1, t + 1);
    bf16x8 af[2], bfr[2];
#pragma unroll
    for (int f = 0; f < 2; ++f) af[f] = *(const bf16x8*)&ldsA[buf][offA[f]];
#pragma unroll
    for (int f = 0; f < 2; ++f) bfr[f] = *(const bf16x8*)&ldsB[buf][offB[f]];
#pragma unroll
    for (int i = 0; i < 2; ++i)
#pragma unroll
      for (int j = 0; j < 2; ++j)
        acc[i][j] = __builtin_amdgcn_mfma_f32_16x16x32_bf16(af[i], bfr[j],
                                                            acc[i][j], 0, 0, 0);
    __syncthreads();
  }

#pragma unroll
  for (int j = 0; j < 2; ++j) {
    const int col = j * 16 + l15;
    if (col < 18) {
      const float bias = b_off[col];
#pragma unroll
      for (int i = 0; i < 2; ++i)
#pragma unroll
        for (int r = 0; r < 4; ++r) {
          const int m = m0 + wid * 32 + i * 16 + l4 * 4 + r;
          off_buf[(size_t)m * 18 + col] = acc[i][j][r] + bias;
        }
    }
  }
}

// ---------------- sampler: bilinear -> S bf16 ----------------
__global__ __launch_bounds__(512) void sampler(const unsigned short* __restrict__ xTbf,
                                               const float* __restrict__ off_buf,
                                               unsigned short* __restrict__ S) {
  const int tid = threadIdx.x;
  const int lane = tid & 63;
  const int ww = __builtin_amdgcn_readfirstlane(tid >> 6);
  const int h = blockIdx.x & 63;
  const int b = blockIdx.x >> 6;
  const int rowbase = (b << 12) + (h << 6);
  const unsigned short* xb = xTbf + ((size_t)b << 20);

  for (int t = ww; t < 576; t += 8) {
    const int w = t / 9, k = t - w * 9;
    const int ky = k / 3, kx = k - ky * 3;
    const float offy = off_buf[(rowbase + w) * 18 + 2 * k];
    const float offx = off_buf[(rowbase + w) * 18 + 2 * k + 1];
    const float sy = offy + (float)(h - 1 + ky);
    const float sx = offx + (float)(w - 1 + kx);
    const float y0f = floorf(sy), x0f = floorf(sx);
    const float ly = sy - y0f, lx = sx - x0f;
    const int y0 = (int)y0f, x0 = (int)x0f;
    const int y1 = y0 + 1, x1 = x0 + 1;
    const float vy0 = (y0 >= 0 && y0 < HW) ? 1.f : 0.f;
    const float vy1 = (y1 >= 0 && y1 < HW) ? 1.f : 0.f;
    const float vx0 = (x0 >= 0 && x0 < HW) ? 1.f : 0.f;
    const float vx1 = (x1 >= 0 && x1 < HW) ? 1.f : 0.f;
    const float w00 = (1.f - ly) * (1.f - lx) * vy0 * vx0;
    const float w01 = (1.f - ly) * lx * vy0 * vx1;
    const float w10 = ly * (1.f - lx) * vy1 * vx0;
    const float w11 = ly * lx * vy1 * vx1;
    const int y0c = min(max(y0, 0), HW - 1), y1c = min(max(y1, 0), HW - 1);
    const int x0c = min(max(x0, 0), HW - 1), x1c = min(max(x1, 0), HW - 1);

    const u16x4 a = *(const u16x4*)(xb + ((((y0c << 6) + x0c) << 8) + lane * 4));
    const u16x4 bv = *(const u16x4*)(xb + ((((y0c << 6) + x1c) << 8) + lane * 4));
    const u16x4 c = *(const u16x4*)(xb + ((((y1c << 6) + x0c) << 8) + lane * 4));
    const u16x4 d = *(const u16x4*)(xb + ((((y1c << 6) + x1c) << 8) + lane * 4));

    u16x4 o;
#pragma unroll
    for (int q = 0; q < 4; ++q)
      o[q] = f2bf(w00 * bf2f(a[q]) + w01 * bf2f(bv[q]) + w10 * bf2f(c[q]) +
                  w11 * bf2f(d[q]));
    *(u16x4*)(S + (size_t)(rowbase + w) * KDIM + k * 256 + lane * 4) = o;
  }
}

// ---------------- dcn_gemm: out[32768x256] = S * W2^T (unchanged, validated) --
__global__ __launch_bounds__(512) void dcn_gemm(
    const unsigned short* __restrict__ S, const unsigned short* __restrict__ W2,
    float* __restrict__ out) {
  __shared__ short ldsA[2][128 * 32];
  __shared__ short ldsB[2][256 * 32];
  const int tid = threadIdx.x;
  const int m0 = blockIdx.x * 128;

  const int rowA = tid >> 2;
  const int scA = (tid & 3) ^ ((rowA >> 1) & 3);
  const unsigned short* srcA = S + (size_t)(m0 + rowA) * KDIM + scA * 8;
  const unsigned short* srcB0 = W2 + (size_t)rowA * KDIM + scA * 8;
  const int rowB1 = 128 + rowA;
  const int scB1 = (tid & 3) ^ ((rowB1 >> 1) & 3);
  const unsigned short* srcB1 = W2 + (size_t)rowB1 * KDIM + scB1 * 8;

  const int lane = tid & 63;
  const int l15 = lane & 15, l4 = lane >> 4;
  const int wid = __builtin_amdgcn_readfirstlane(tid >> 6);
  const int wm = wid & 1, wn = wid >> 1;

  int offA[4], offB[4];
#pragma unroll
  for (int f = 0; f < 4; ++f) {
    int rA = wm * 64 + f * 16 + l15;
    offA[f] = rA * 32 + ((l4 ^ ((rA >> 1) & 3)) << 3);
    int rB = wn * 64 + f * 16 + l15;
    offB[f] = rB * 32 + ((l4 ^ ((rB >> 1) & 3)) << 3);
  }

  const f32x4 z = {0.f, 0.f, 0.f, 0.f};
  f32x4 acc[4][4];
#pragma unroll
  for (int i = 0; i < 4; ++i)
#pragma unroll
    for (int j = 0; j < 4; ++j) acc[i][j] = z;

  GLL16(srcA, &ldsA[0][tid * 8]);
  GLL16(srcB0, &ldsB[0][tid * 8]);
  GLL16(srcB1, &ldsB[0][(512 + tid) * 8]);
  __syncthreads();

  for (int t = 0; t < 72; ++t) {
    const int buf = t & 1;
    if (t < 71) {
      const int k0 = (t + 1) * 32;
      GLL16(srcA + k0, &ldsA[buf ^ 1][tid * 8]);
      GLL16(srcB0 + k0, &ldsB[buf ^ 1][tid * 8]);
      GLL16(srcB1 + k0, &ldsB[buf ^ 1][(512 + tid) * 8]);
    }
    bf16x8 af[4], bfr[4];
#pragma unroll
    for (int f = 0; f < 4; ++f) af[f] = *(const bf16x8*)&ldsA[buf][offA[f]];
#pragma unroll
    for (int f = 0; f < 4; ++f) bfr[f] = *(const bf16x8*)&ldsB[buf][offB[f]];
#pragma unroll
    for (int i = 0; i < 4; ++i)
#pragma unroll
      for (int j = 0; j < 4; ++j)
        acc[i][j] = __builtin_amdgcn_mfma_f32_16x16x32_bf16(af[i], bfr[j],
                                                            acc[i][j], 0, 0, 0);
    __syncthreads();
  }

#pragma unroll
  for (int i = 0; i < 4; ++i) {
    const int m = m0 + wm * 64 + i * 16 + l4 * 4;
    const int bb = m >> 12;
    const int pos = m & 4095;
#pragma unroll
    for (int j = 0; j < 4; ++j) {
      const int o = wn * 64 + j * 16 + l15;
      *(f32x4*)(out + (((size_t)bb * OCH + o) << 12) + pos) = acc[i][j];
    }
  }
}

extern "C" void kernel_launch(void* const* d_in, const int* in_sizes, int n_in,
                              void* d_out, int out_size, void* d_ws,
                              size_t ws_size, hipStream_t stream) {
  const float* x = (const float*)d_in[0];
  const float* w_off = (const float*)d_in[1];
  const float* b_off = (const float*)d_in[2];
  const float* w_dcn = (const float*)d_in[3];
  float* out = (float*)d_out;

  char* ws = (char*)d_ws;
  float* off_buf = (float*)(ws);                            //  2,359,296 B
  unsigned short* Wop = (unsigned short*)(ws + 2359296);    //    147,456 B
  unsigned short* zp = (unsigned short*)(ws + 2506752);     //      1,024 B
  unsigned short* W2 = (unsigned short*)(ws + 2507776);     //  1,179,648 B
  unsigned short* xTbf = (unsigned short*)(ws + 3687424);   // 16,777,216 B
  unsigned short* S = (unsigned short*)(ws + 20464640);     // 150,994,944 B
  // total 171,459,584 B

  prep<<<2304, 256, 0, stream>>>(w_dcn, w_off, W2, Wop, zp);
  xpose<<<2048, 256, 0, stream>>>(x, xTbf);
  offset_gemm<<<256, 256, 0, stream>>>(xTbf, Wop, zp, b_off, off_buf);
  sampler<<<BB * HW, 512, 0, stream>>>(xTbf, off_buf, S);
  dcn_gemm<<<256, 512, 0, stream>>>(S, W2, out);
}

// Round 4
// 139.418 us; speedup vs baseline: 6.6791x; 1.2302x over previous
//
#include <hip/hip_runtime.h>
#include <hip/hip_bf16.h>

// Deformable conv via FUSED implicit GEMM on MFMA.
// B=8, C=256, H=W=64, O=256, K=3.
// Stages: prep (weights->bf16, zero page) ; xpose (x -> bf16 NHWC) ;
//         offset_gemm (M=32768,N=32(18),K=2304 fixed-grid im2col) ;
//         dcn_fused  (bilinear-sample A-tile in-kernel + mfma GEMM, no S matrix).

#define HW 64
#define CCH 256
#define OCH 256
#define BB 8
#define KDIM 2304  // 9 * 256, order kk*256 + c

typedef __attribute__((ext_vector_type(8))) short bf16x8;
typedef __attribute__((ext_vector_type(8))) unsigned short u16x8;
typedef __attribute__((ext_vector_type(4))) float f32x4;
typedef __attribute__((ext_vector_type(4))) unsigned short u16x4;
typedef __attribute__((ext_vector_type(4))) unsigned int u32x4;
typedef __attribute__((ext_vector_type(4))) int i32x4;

static __device__ inline unsigned short f2bf(float f) {
  unsigned u = __builtin_bit_cast(unsigned, f);
  u += 0x7FFFu + ((u >> 16) & 1u);  // RNE
  return (unsigned short)(u >> 16);
}
static __device__ inline float bf2f(unsigned short s) {
  return __builtin_bit_cast(float, (unsigned)s << 16);
}
static __device__ inline unsigned cvt_pk_bf16(float lo, float hi) {
  unsigned r;
  asm("v_cvt_pk_bf16_f32 %0, %1, %2" : "=v"(r) : "v"(lo), "v"(hi));
  return r;
}

#define GLL16(gsrc, ldst)                                                      \
  __builtin_amdgcn_global_load_lds(                                           \
      (const __attribute__((address_space(1))) void*)(gsrc),                  \
      (__attribute__((address_space(3))) void*)(ldst), 16, 0, 0)

// ---------------- prep ----------------
__global__ __launch_bounds__(256) void prep(const float* __restrict__ w_dcn,
                                            const float* __restrict__ w_off,
                                            unsigned short* __restrict__ W2,
                                            unsigned short* __restrict__ Wop,
                                            unsigned short* __restrict__ zp) {
  int i = blockIdx.x * 256 + threadIdx.x;
  if (i < 9 * 256 * 256) {
    int o = i / KDIM;
    int r = i - o * KDIM;
    int kk = r >> 8, c = r & 255;
    W2[i] = f2bf(w_dcn[((o << 8) + c) * 9 + kk]);
  }
  if (i < 32 * KDIM) {
    int n = i / KDIM;
    int r = i - n * KDIM;
    int kk = r >> 8, c = r & 255;
    Wop[i] = (n < 18) ? f2bf(w_off[((n << 8) + c) * 9 + kk]) : (unsigned short)0;
  }
  if (i < 512) zp[i] = 0;
}

// ---------------- xpose: NCHW f32 -> NHWC bf16 ----------------
__global__ __launch_bounds__(256) void xpose(const float* __restrict__ x,
                                             unsigned short* __restrict__ xTbf) {
  __shared__ float t[64][65];
  const int tid = threadIdx.x;
  const int bid = blockIdx.x;
  const int ct = bid & 3;
  const int pt = (bid >> 2) & 63;
  const int b = bid >> 8;
#pragma unroll
  for (int i = 0; i < 16; ++i) {
    int cl = i * 4 + (tid >> 6);
    int p = tid & 63;
    t[cl][p] = x[(((b << 8) + ct * 64 + cl) << 12) + pt * 64 + p];
  }
  __syncthreads();
#pragma unroll
  for (int i = 0; i < 4; ++i) {
    int pl = i * 16 + (tid >> 4);
    int c4 = (tid & 15) * 4;
    u16x4 v;
    v[0] = f2bf(t[c4][pl]);
    v[1] = f2bf(t[c4 + 1][pl]);
    v[2] = f2bf(t[c4 + 2][pl]);
    v[3] = f2bf(t[c4 + 3][pl]);
    *(u16x4*)(xTbf + (((size_t)((b << 12) + pt * 64 + pl)) << 8) + ct * 64 + c4) = v;
  }
}

// ---------------- offset_gemm (unchanged, validated) ----------------
__global__ __launch_bounds__(256) void offset_gemm(
    const unsigned short* __restrict__ xTbf, const unsigned short* __restrict__ Wop,
    const unsigned short* __restrict__ zp, const float* __restrict__ b_off,
    float* __restrict__ off_buf) {
  __shared__ short ldsA[2][128 * 32];
  __shared__ short ldsB[2][32 * 32];
  const int tid = threadIdx.x;
  const int lane = tid & 63;
  const int wid = __builtin_amdgcn_readfirstlane(tid >> 6);
  const int m0 = blockIdx.x * 128;
  const int b = m0 >> 12;
  const unsigned short* xb = xTbf + ((size_t)b << 20);

  int hA[2], wA[2], scA[2];
#pragma unroll
  for (int g = 0; g < 2; ++g) {
    int r = wid * 32 + g * 16 + (lane >> 2);
    int pos = (m0 & 4095) + r;
    hA[g] = pos >> 6;
    wA[g] = pos & 63;
    scA[g] = ((lane & 3) ^ ((r >> 1) & 3)) * 8;
  }
  const int rB = wid * 16 + (lane >> 2);
  const unsigned short* srcB =
      Wop + (size_t)rB * KDIM + ((lane & 3) ^ ((rB >> 1) & 3)) * 8;

  const int l15 = lane & 15, l4 = lane >> 4;
  int offA[2], offB[2];
#pragma unroll
  for (int f = 0; f < 2; ++f) {
    int rA = wid * 32 + f * 16 + l15;
    offA[f] = rA * 32 + ((l4 ^ ((rA >> 1) & 3)) << 3);
    int rb = f * 16 + l15;
    offB[f] = rb * 32 + ((l4 ^ ((rb >> 1) & 3)) << 3);
  }

  const f32x4 z = {0.f, 0.f, 0.f, 0.f};
  f32x4 acc[2][2];
#pragma unroll
  for (int i = 0; i < 2; ++i)
#pragma unroll
    for (int j = 0; j < 2; ++j) acc[i][j] = z;

  auto stage = [&](int buf, int t) {
    const int kk = t >> 3;
    const int c0 = (t & 7) * 32;
    const int dy = kk / 3 - 1, dx = kk - (kk / 3) * 3 - 1;
#pragma unroll
    for (int g = 0; g < 2; ++g) {
      const int y = hA[g] + dy, xx = wA[g] + dx;
      const bool valid = ((unsigned)y < 64u) && ((unsigned)xx < 64u);
      const unsigned short* src =
          valid ? xb + ((((y << 6) + xx) << 8) + c0 + scA[g]) : zp + scA[g];
      GLL16(src, &ldsA[buf][((wid * 2 + g) * 64 + lane) * 8]);
    }
    if (wid < 2) GLL16(srcB + t * 32, &ldsB[buf][(wid * 64 + lane) * 8]);
  };

  stage(0, 0);
  __syncthreads();

  for (int t = 0; t < 72; ++t) {
    const int buf = t & 1;
    if (t < 71) stage(buf ^ 1, t + 1);
    bf16x8 af[2], bfr[2];
#pragma unroll
    for (int f = 0; f < 2; ++f) af[f] = *(const bf16x8*)&ldsA[buf][offA[f]];
#pragma unroll
    for (int f = 0; f < 2; ++f) bfr[f] = *(const bf16x8*)&ldsB[buf][offB[f]];
#pragma unroll
    for (int i = 0; i < 2; ++i)
#pragma unroll
      for (int j = 0; j < 2; ++j)
        acc[i][j] = __builtin_amdgcn_mfma_f32_16x16x32_bf16(af[i], bfr[j],
                                                            acc[i][j], 0, 0, 0);
    __syncthreads();
  }

#pragma unroll
  for (int j = 0; j < 2; ++j) {
    const int col = j * 16 + l15;
    if (col < 18) {
      const float bias = b_off[col];
#pragma unroll
      for (int i = 0; i < 2; ++i)
#pragma unroll
        for (int r = 0; r < 4; ++r) {
          const int m = m0 + wid * 32 + i * 16 + l4 * 4 + r;
          off_buf[(size_t)m * 18 + col] = acc[i][j][r] + bias;
        }
    }
  }
}

// ---------------- dcn_fused ----------------
// out[m][o] = sum_k A[m][k] * W2[o][k], A sampled in-kernel (no S matrix).
// 512 threads (8 waves: wm=wid&1, wn=wid>>1). BM=128, BN=256, BK=32, dbuf.
// Sampling role: thread -> row r=tid>>2, chunk g=tid&3 (8 channels).
__global__ __launch_bounds__(512) void dcn_fused(
    const unsigned short* __restrict__ xTbf, const float* __restrict__ off_buf,
    const unsigned short* __restrict__ W2, float* __restrict__ out) {
  __shared__ f32x4 sww[128][9];   // bilinear weights
  __shared__ i32x4 sad[128][9];   // clamped corner base offsets (elements)
  __shared__ short ldsA[2][128 * 32];
  __shared__ short ldsB[2][256 * 32];

  const int tid = threadIdx.x;
  const int lane = tid & 63;
  const int wid = __builtin_amdgcn_readfirstlane(tid >> 6);
  const int m0 = blockIdx.x * 128;
  const int b = m0 >> 12;
  const unsigned short* xb = xTbf + ((size_t)b << 20);

  // ---- phase 0: sampling params for 128 rows x 9 taps ----
  for (int idx = tid; idx < 128 * 9; idx += 512) {
    const int r = idx / 9, k = idx - (idx / 9) * 9;
    const int ky = k / 3, kx = k - ky * 3;
    const int pos = (m0 & 4095) + r;
    const int h = pos >> 6, w = pos & 63;
    const float offy = off_buf[(size_t)(m0 + r) * 18 + 2 * k];
    const float offx = off_buf[(size_t)(m0 + r) * 18 + 2 * k + 1];
    const float sy = offy + (float)(h - 1 + ky);
    const float sx = offx + (float)(w - 1 + kx);
    const float y0f = floorf(sy), x0f = floorf(sx);
    const float ly = sy - y0f, lx = sx - x0f;
    const int y0 = (int)y0f, x0 = (int)x0f;
    const int y1 = y0 + 1, x1 = x0 + 1;
    const float vy0 = ((unsigned)y0 < 64u) ? 1.f : 0.f;
    const float vy1 = ((unsigned)y1 < 64u) ? 1.f : 0.f;
    const float vx0 = ((unsigned)x0 < 64u) ? 1.f : 0.f;
    const float vx1 = ((unsigned)x1 < 64u) ? 1.f : 0.f;
    f32x4 wv;
    wv[0] = (1.f - ly) * (1.f - lx) * vy0 * vx0;
    wv[1] = (1.f - ly) * lx * vy0 * vx1;
    wv[2] = ly * (1.f - lx) * vy1 * vx0;
    wv[3] = ly * lx * vy1 * vx1;
    const int y0c = min(max(y0, 0), HW - 1), y1c = min(max(y1, 0), HW - 1);
    const int x0c = min(max(x0, 0), HW - 1), x1c = min(max(x1, 0), HW - 1);
    i32x4 av;
    av[0] = ((y0c << 6) + x0c) << 8;
    av[1] = ((y0c << 6) + x1c) << 8;
    av[2] = ((y1c << 6) + x0c) << 8;
    av[3] = ((y1c << 6) + x1c) << 8;
    sww[r][k] = wv;
    sad[r][k] = av;
  }

  // ---- GEMM roles ----
  const int r = tid >> 2, g = tid & 3;                 // sampling role
  const int dstA = (r * 4 + (g ^ ((r >> 1) & 3))) * 8; // swizzled A slot
  const int rowB = tid >> 2;
  const int scB = (tid & 3) ^ ((rowB >> 1) & 3);
  const unsigned short* srcB0 = W2 + (size_t)rowB * KDIM + scB * 8;
  const int rowB1 = 128 + rowB;
  const int scB1 = (tid & 3) ^ ((rowB1 >> 1) & 3);
  const unsigned short* srcB1 = W2 + (size_t)rowB1 * KDIM + scB1 * 8;

  const int l15 = lane & 15, l4 = lane >> 4;
  const int wm = wid & 1, wn = wid >> 1;
  int offA[4], offB[4];
#pragma unroll
  for (int f = 0; f < 4; ++f) {
    int rA = wm * 64 + f * 16 + l15;
    offA[f] = rA * 32 + ((l4 ^ ((rA >> 1) & 3)) << 3);
    int rB = wn * 64 + f * 16 + l15;
    offB[f] = rB * 32 + ((l4 ^ ((rB >> 1) & 3)) << 3);
  }

  const f32x4 z = {0.f, 0.f, 0.f, 0.f};
  f32x4 acc[4][4];
#pragma unroll
  for (int i = 0; i < 4; ++i)
#pragma unroll
    for (int j = 0; j < 4; ++j) acc[i][j] = z;

  __syncthreads();  // params visible

  // per-thread param regs for current prefetch kk
  f32x4 wv = sww[r][0];
  i32x4 av = sad[r][0];

  auto lerp_pack = [&](const u16x8& c00, const u16x8& c01, const u16x8& c10,
                       const u16x8& c11, const f32x4& wt) -> bf16x8 {
    u32x4 words;
#pragma unroll
    for (int j = 0; j < 4; ++j) {
      float f0 = wt[0] * bf2f(c00[2 * j]) + wt[1] * bf2f(c01[2 * j]) +
                 wt[2] * bf2f(c10[2 * j]) + wt[3] * bf2f(c11[2 * j]);
      float f1 = wt[0] * bf2f(c00[2 * j + 1]) + wt[1] * bf2f(c01[2 * j + 1]) +
                 wt[2] * bf2f(c10[2 * j + 1]) + wt[3] * bf2f(c11[2 * j + 1]);
      words[j] = cvt_pk_bf16(f0, f1);
    }
    return __builtin_bit_cast(bf16x8, words);
  };

  // ---- prologue: stage tile 0 ----
  {
    const int ch = g * 8;
    u16x8 c00 = *(const u16x8*)(xb + av[0] + ch);
    u16x8 c01 = *(const u16x8*)(xb + av[1] + ch);
    u16x8 c10 = *(const u16x8*)(xb + av[2] + ch);
    u16x8 c11 = *(const u16x8*)(xb + av[3] + ch);
    *(bf16x8*)&ldsA[0][dstA] = lerp_pack(c00, c01, c10, c11, wv);
    GLL16(srcB0, &ldsB[0][tid * 8]);
    GLL16(srcB1, &ldsB[0][(512 + tid) * 8]);
  }
  __syncthreads();

  // ---- main loop ----
  for (int t = 0; t < 72; ++t) {
    const int buf = t & 1;
    u16x8 c00, c01, c10, c11;
    f32x4 wcur;
    if (t < 71) {
      const int tn = t + 1;
      if ((tn & 7) == 0) {  // next kk
        const int kk = tn >> 3;
        wv = sww[r][kk];
        av = sad[r][kk];
      }
      const int ch = (tn & 7) * 32 + g * 8;
      c00 = *(const u16x8*)(xb + av[0] + ch);  // issue early (T14)
      c01 = *(const u16x8*)(xb + av[1] + ch);
      c10 = *(const u16x8*)(xb + av[2] + ch);
      c11 = *(const u16x8*)(xb + av[3] + ch);
      wcur = wv;
      GLL16(srcB0 + tn * 32, &ldsB[buf ^ 1][tid * 8]);
      GLL16(srcB1 + tn * 32, &ldsB[buf ^ 1][(512 + tid) * 8]);
    }

    bf16x8 af[4], bfr[4];
#pragma unroll
    for (int f = 0; f < 4; ++f) af[f] = *(const bf16x8*)&ldsA[buf][offA[f]];
#pragma unroll
    for (int f = 0; f < 4; ++f) bfr[f] = *(const bf16x8*)&ldsB[buf][offB[f]];
#pragma unroll
    for (int i = 0; i < 4; ++i)
#pragma unroll
      for (int j = 0; j < 4; ++j)
        acc[i][j] = __builtin_amdgcn_mfma_f32_16x16x32_bf16(af[i], bfr[j],
                                                            acc[i][j], 0, 0, 0);

    if (t < 71)  // lerp late: gather latency hidden under the MFMAs above
      *(bf16x8*)&ldsA[buf ^ 1][dstA] = lerp_pack(c00, c01, c10, c11, wcur);
    __syncthreads();
  }

  // ---- epilogue ----
#pragma unroll
  for (int i = 0; i < 4; ++i) {
    const int m = m0 + wm * 64 + i * 16 + l4 * 4;
    const int bb = m >> 12;
    const int pos = m & 4095;
#pragma unroll
    for (int j = 0; j < 4; ++j) {
      const int o = wn * 64 + j * 16 + l15;
      *(f32x4*)(out + (((size_t)bb * OCH + o) << 12) + pos) = acc[i][j];
    }
  }
}

extern "C" void kernel_launch(void* const* d_in, const int* in_sizes, int n_in,
                              void* d_out, int out_size, void* d_ws,
                              size_t ws_size, hipStream_t stream) {
  const float* x = (const float*)d_in[0];
  const float* w_off = (const float*)d_in[1];
  const float* b_off = (const float*)d_in[2];
  const float* w_dcn = (const float*)d_in[3];
  float* out = (float*)d_out;

  char* ws = (char*)d_ws;
  float* off_buf = (float*)(ws);                            //  2,359,296 B
  unsigned short* Wop = (unsigned short*)(ws + 2359296);    //    147,456 B
  unsigned short* zp = (unsigned short*)(ws + 2506752);     //      1,024 B
  unsigned short* W2 = (unsigned short*)(ws + 2507776);     //  1,179,648 B
  unsigned short* xTbf = (unsigned short*)(ws + 3687424);   // 16,777,216 B
  // total 20,464,640 B

  prep<<<2304, 256, 0, stream>>>(w_dcn, w_off, W2, Wop, zp);
  xpose<<<2048, 256, 0, stream>>>(x, xTbf);
  offset_gemm<<<256, 256, 0, stream>>>(xTbf, Wop, zp, b_off, off_buf);
  dcn_fused<<<256, 512, 0, stream>>>(xTbf, off_buf, W2, out);
}

// Round 5
// 133.193 us; speedup vs baseline: 6.9912x; 1.0467x over previous
//
#include <hip/hip_runtime.h>
#include <hip/hip_bf16.h>

// Deformable conv via FUSED implicit GEMM on MFMA.
// B=8, C=256, H=W=64, O=256, K=3.
// Stages: prep ; xpose (x -> bf16 NHWC) ; offset_gemm ; dcn_fused.
// R5: XCD-bijective block swizzle on offset_gemm + dcn_fused so each XCD's
//     32 blocks own exactly one image (2MB, L2-resident gathers).

#define HW 64
#define CCH 256
#define OCH 256
#define BB 8
#define KDIM 2304  // 9 * 256, order kk*256 + c

typedef __attribute__((ext_vector_type(8))) short bf16x8;
typedef __attribute__((ext_vector_type(8))) unsigned short u16x8;
typedef __attribute__((ext_vector_type(4))) float f32x4;
typedef __attribute__((ext_vector_type(4))) unsigned short u16x4;
typedef __attribute__((ext_vector_type(4))) unsigned int u32x4;
typedef __attribute__((ext_vector_type(4))) int i32x4;

static __device__ inline unsigned short f2bf(float f) {
  unsigned u = __builtin_bit_cast(unsigned, f);
  u += 0x7FFFu + ((u >> 16) & 1u);  // RNE
  return (unsigned short)(u >> 16);
}
static __device__ inline float bf2f(unsigned short s) {
  return __builtin_bit_cast(float, (unsigned)s << 16);
}
static __device__ inline unsigned cvt_pk_bf16(float lo, float hi) {
  unsigned r;
  asm("v_cvt_pk_bf16_f32 %0, %1, %2" : "=v"(r) : "v"(lo), "v"(hi));
  return r;
}

#define GLL16(gsrc, ldst)                                                      \
  __builtin_amdgcn_global_load_lds(                                           \
      (const __attribute__((address_space(1))) void*)(gsrc),                  \
      (__attribute__((address_space(3))) void*)(ldst), 16, 0, 0)

// XCD-bijective swizzle for nwg=256 on 8 XCDs: XCD k gets blocks [32k,32k+32).
static __device__ inline int xcd_swz256(int bid) {
  return (bid & 7) * 32 + (bid >> 3);
}

// ---------------- prep ----------------
__global__ __launch_bounds__(256) void prep(const float* __restrict__ w_dcn,
                                            const float* __restrict__ w_off,
                                            unsigned short* __restrict__ W2,
                                            unsigned short* __restrict__ Wop,
                                            unsigned short* __restrict__ zp) {
  int i = blockIdx.x * 256 + threadIdx.x;
  if (i < 9 * 256 * 256) {
    int o = i / KDIM;
    int r = i - o * KDIM;
    int kk = r >> 8, c = r & 255;
    W2[i] = f2bf(w_dcn[((o << 8) + c) * 9 + kk]);
  }
  if (i < 32 * KDIM) {
    int n = i / KDIM;
    int r = i - n * KDIM;
    int kk = r >> 8, c = r & 255;
    Wop[i] = (n < 18) ? f2bf(w_off[((n << 8) + c) * 9 + kk]) : (unsigned short)0;
  }
  if (i < 512) zp[i] = 0;
}

// ---------------- xpose: NCHW f32 -> NHWC bf16 ----------------
__global__ __launch_bounds__(256) void xpose(const float* __restrict__ x,
                                             unsigned short* __restrict__ xTbf) {
  __shared__ float t[64][65];
  const int tid = threadIdx.x;
  const int bid = blockIdx.x;
  const int ct = bid & 3;
  const int pt = (bid >> 2) & 63;
  const int b = bid >> 8;
#pragma unroll
  for (int i = 0; i < 16; ++i) {
    int cl = i * 4 + (tid >> 6);
    int p = tid & 63;
    t[cl][p] = x[(((b << 8) + ct * 64 + cl) << 12) + pt * 64 + p];
  }
  __syncthreads();
#pragma unroll
  for (int i = 0; i < 4; ++i) {
    int pl = i * 16 + (tid >> 4);
    int c4 = (tid & 15) * 4;
    u16x4 v;
    v[0] = f2bf(t[c4][pl]);
    v[1] = f2bf(t[c4 + 1][pl]);
    v[2] = f2bf(t[c4 + 2][pl]);
    v[3] = f2bf(t[c4 + 3][pl]);
    *(u16x4*)(xTbf + (((size_t)((b << 12) + pt * 64 + pl)) << 8) + ct * 64 + c4) = v;
  }
}

// ---------------- offset_gemm ----------------
__global__ __launch_bounds__(256) void offset_gemm(
    const unsigned short* __restrict__ xTbf, const unsigned short* __restrict__ Wop,
    const unsigned short* __restrict__ zp, const float* __restrict__ b_off,
    float* __restrict__ off_buf) {
  __shared__ short ldsA[2][128 * 32];
  __shared__ short ldsB[2][32 * 32];
  const int tid = threadIdx.x;
  const int lane = tid & 63;
  const int wid = __builtin_amdgcn_readfirstlane(tid >> 6);
  const int m0 = xcd_swz256(blockIdx.x) * 128;
  const int b = m0 >> 12;
  const unsigned short* xb = xTbf + ((size_t)b << 20);

  int hA[2], wA[2], scA[2];
#pragma unroll
  for (int g = 0; g < 2; ++g) {
    int r = wid * 32 + g * 16 + (lane >> 2);
    int pos = (m0 & 4095) + r;
    hA[g] = pos >> 6;
    wA[g] = pos & 63;
    scA[g] = ((lane & 3) ^ ((r >> 1) & 3)) * 8;
  }
  const int rB = wid * 16 + (lane >> 2);
  const unsigned short* srcB =
      Wop + (size_t)rB * KDIM + ((lane & 3) ^ ((rB >> 1) & 3)) * 8;

  const int l15 = lane & 15, l4 = lane >> 4;
  int offA[2], offB[2];
#pragma unroll
  for (int f = 0; f < 2; ++f) {
    int rA = wid * 32 + f * 16 + l15;
    offA[f] = rA * 32 + ((l4 ^ ((rA >> 1) & 3)) << 3);
    int rb = f * 16 + l15;
    offB[f] = rb * 32 + ((l4 ^ ((rb >> 1) & 3)) << 3);
  }

  const f32x4 z = {0.f, 0.f, 0.f, 0.f};
  f32x4 acc[2][2];
#pragma unroll
  for (int i = 0; i < 2; ++i)
#pragma unroll
    for (int j = 0; j < 2; ++j) acc[i][j] = z;

  auto stage = [&](int buf, int t) {
    const int kk = t >> 3;
    const int c0 = (t & 7) * 32;
    const int dy = kk / 3 - 1, dx = kk - (kk / 3) * 3 - 1;
#pragma unroll
    for (int g = 0; g < 2; ++g) {
      const int y = hA[g] + dy, xx = wA[g] + dx;
      const bool valid = ((unsigned)y < 64u) && ((unsigned)xx < 64u);
      const unsigned short* src =
          valid ? xb + ((((y << 6) + xx) << 8) + c0 + scA[g]) : zp + scA[g];
      GLL16(src, &ldsA[buf][((wid * 2 + g) * 64 + lane) * 8]);
    }
    if (wid < 2) GLL16(srcB + t * 32, &ldsB[buf][(wid * 64 + lane) * 8]);
  };

  stage(0, 0);
  __syncthreads();

  for (int t = 0; t < 72; ++t) {
    const int buf = t & 1;
    if (t < 71) stage(buf ^ 1, t + 1);
    bf16x8 af[2], bfr[2];
#pragma unroll
    for (int f = 0; f < 2; ++f) af[f] = *(const bf16x8*)&ldsA[buf][offA[f]];
#pragma unroll
    for (int f = 0; f < 2; ++f) bfr[f] = *(const bf16x8*)&ldsB[buf][offB[f]];
#pragma unroll
    for (int i = 0; i < 2; ++i)
#pragma unroll
      for (int j = 0; j < 2; ++j)
        acc[i][j] = __builtin_amdgcn_mfma_f32_16x16x32_bf16(af[i], bfr[j],
                                                            acc[i][j], 0, 0, 0);
    __syncthreads();
  }

#pragma unroll
  for (int j = 0; j < 2; ++j) {
    const int col = j * 16 + l15;
    if (col < 18) {
      const float bias = b_off[col];
#pragma unroll
      for (int i = 0; i < 2; ++i)
#pragma unroll
        for (int r = 0; r < 4; ++r) {
          const int m = m0 + wid * 32 + i * 16 + l4 * 4 + r;
          off_buf[(size_t)m * 18 + col] = acc[i][j][r] + bias;
        }
    }
  }
}

// ---------------- dcn_fused ----------------
__global__ __launch_bounds__(512) void dcn_fused(
    const unsigned short* __restrict__ xTbf, const float* __restrict__ off_buf,
    const unsigned short* __restrict__ W2, float* __restrict__ out) {
  __shared__ f32x4 sww[128][9];   // bilinear weights
  __shared__ i32x4 sad[128][9];   // clamped corner base offsets (elements)
  __shared__ short ldsA[2][128 * 32];
  __shared__ short ldsB[2][256 * 32];

  const int tid = threadIdx.x;
  const int lane = tid & 63;
  const int wid = __builtin_amdgcn_readfirstlane(tid >> 6);
  const int m0 = xcd_swz256(blockIdx.x) * 128;
  const int b = m0 >> 12;
  const unsigned short* xb = xTbf + ((size_t)b << 20);

  // ---- phase 0: sampling params for 128 rows x 9 taps ----
  for (int idx = tid; idx < 128 * 9; idx += 512) {
    const int r = idx / 9, k = idx - (idx / 9) * 9;
    const int ky = k / 3, kx = k - ky * 3;
    const int pos = (m0 & 4095) + r;
    const int h = pos >> 6, w = pos & 63;
    const float offy = off_buf[(size_t)(m0 + r) * 18 + 2 * k];
    const float offx = off_buf[(size_t)(m0 + r) * 18 + 2 * k + 1];
    const float sy = offy + (float)(h - 1 + ky);
    const float sx = offx + (float)(w - 1 + kx);
    const float y0f = floorf(sy), x0f = floorf(sx);
    const float ly = sy - y0f, lx = sx - x0f;
    const int y0 = (int)y0f, x0 = (int)x0f;
    const int y1 = y0 + 1, x1 = x0 + 1;
    const float vy0 = ((unsigned)y0 < 64u) ? 1.f : 0.f;
    const float vy1 = ((unsigned)y1 < 64u) ? 1.f : 0.f;
    const float vx0 = ((unsigned)x0 < 64u) ? 1.f : 0.f;
    const float vx1 = ((unsigned)x1 < 64u) ? 1.f : 0.f;
    f32x4 wv;
    wv[0] = (1.f - ly) * (1.f - lx) * vy0 * vx0;
    wv[1] = (1.f - ly) * lx * vy0 * vx1;
    wv[2] = ly * (1.f - lx) * vy1 * vx0;
    wv[3] = ly * lx * vy1 * vx1;
    const int y0c = min(max(y0, 0), HW - 1), y1c = min(max(y1, 0), HW - 1);
    const int x0c = min(max(x0, 0), HW - 1), x1c = min(max(x1, 0), HW - 1);
    i32x4 av;
    av[0] = ((y0c << 6) + x0c) << 8;
    av[1] = ((y0c << 6) + x1c) << 8;
    av[2] = ((y1c << 6) + x0c) << 8;
    av[3] = ((y1c << 6) + x1c) << 8;
    sww[r][k] = wv;
    sad[r][k] = av;
  }

  // ---- GEMM roles ----
  const int r = tid >> 2, g = tid & 3;                 // sampling role
  const int dstA = (r * 4 + (g ^ ((r >> 1) & 3))) * 8; // swizzled A slot
  const int rowB = tid >> 2;
  const int scB = (tid & 3) ^ ((rowB >> 1) & 3);
  const unsigned short* srcB0 = W2 + (size_t)rowB * KDIM + scB * 8;
  const int rowB1 = 128 + rowB;
  const int scB1 = (tid & 3) ^ ((rowB1 >> 1) & 3);
  const unsigned short* srcB1 = W2 + (size_t)rowB1 * KDIM + scB1 * 8;

  const int l15 = lane & 15, l4 = lane >> 4;
  const int wm = wid & 1, wn = wid >> 1;
  int offA[4], offB[4];
#pragma unroll
  for (int f = 0; f < 4; ++f) {
    int rA = wm * 64 + f * 16 + l15;
    offA[f] = rA * 32 + ((l4 ^ ((rA >> 1) & 3)) << 3);
    int rB = wn * 64 + f * 16 + l15;
    offB[f] = rB * 32 + ((l4 ^ ((rB >> 1) & 3)) << 3);
  }

  const f32x4 z = {0.f, 0.f, 0.f, 0.f};
  f32x4 acc[4][4];
#pragma unroll
  for (int i = 0; i < 4; ++i)
#pragma unroll
    for (int j = 0; j < 4; ++j) acc[i][j] = z;

  __syncthreads();  // params visible

  f32x4 wv = sww[r][0];
  i32x4 av = sad[r][0];

  auto lerp_pack = [&](const u16x8& c00, const u16x8& c01, const u16x8& c10,
                       const u16x8& c11, const f32x4& wt) -> bf16x8 {
    u32x4 words;
#pragma unroll
    for (int j = 0; j < 4; ++j) {
      float f0 = wt[0] * bf2f(c00[2 * j]) + wt[1] * bf2f(c01[2 * j]) +
                 wt[2] * bf2f(c10[2 * j]) + wt[3] * bf2f(c11[2 * j]);
      float f1 = wt[0] * bf2f(c00[2 * j + 1]) + wt[1] * bf2f(c01[2 * j + 1]) +
                 wt[2] * bf2f(c10[2 * j + 1]) + wt[3] * bf2f(c11[2 * j + 1]);
      words[j] = cvt_pk_bf16(f0, f1);
    }
    return __builtin_bit_cast(bf16x8, words);
  };

  // ---- prologue: stage tile 0 ----
  {
    const int ch = g * 8;
    u16x8 c00 = *(const u16x8*)(xb + av[0] + ch);
    u16x8 c01 = *(const u16x8*)(xb + av[1] + ch);
    u16x8 c10 = *(const u16x8*)(xb + av[2] + ch);
    u16x8 c11 = *(const u16x8*)(xb + av[3] + ch);
    *(bf16x8*)&ldsA[0][dstA] = lerp_pack(c00, c01, c10, c11, wv);
    GLL16(srcB0, &ldsB[0][tid * 8]);
    GLL16(srcB1, &ldsB[0][(512 + tid) * 8]);
  }
  __syncthreads();

  // ---- main loop ----
  for (int t = 0; t < 72; ++t) {
    const int buf = t & 1;
    u16x8 c00, c01, c10, c11;
    f32x4 wcur;
    if (t < 71) {
      const int tn = t + 1;
      if ((tn & 7) == 0) {  // next kk
        const int kk = tn >> 3;
        wv = sww[r][kk];
        av = sad[r][kk];
      }
      const int ch = (tn & 7) * 32 + g * 8;
      c00 = *(const u16x8*)(xb + av[0] + ch);  // issue early (T14)
      c01 = *(const u16x8*)(xb + av[1] + ch);
      c10 = *(const u16x8*)(xb + av[2] + ch);
      c11 = *(const u16x8*)(xb + av[3] + ch);
      wcur = wv;
      GLL16(srcB0 + tn * 32, &ldsB[buf ^ 1][tid * 8]);
      GLL16(srcB1 + tn * 32, &ldsB[buf ^ 1][(512 + tid) * 8]);
    }

    bf16x8 af[4], bfr[4];
#pragma unroll
    for (int f = 0; f < 4; ++f) af[f] = *(const bf16x8*)&ldsA[buf][offA[f]];
#pragma unroll
    for (int f = 0; f < 4; ++f) bfr[f] = *(const bf16x8*)&ldsB[buf][offB[f]];
#pragma unroll
    for (int i = 0; i < 4; ++i)
#pragma unroll
      for (int j = 0; j < 4; ++j)
        acc[i][j] = __builtin_amdgcn_mfma_f32_16x16x32_bf16(af[i], bfr[j],
                                                            acc[i][j], 0, 0, 0);

    if (t < 71)  // lerp late: gather latency hidden under the MFMAs above
      *(bf16x8*)&ldsA[buf ^ 1][dstA] = lerp_pack(c00, c01, c10, c11, wcur);
    __syncthreads();
  }

  // ---- epilogue ----
#pragma unroll
  for (int i = 0; i < 4; ++i) {
    const int m = m0 + wm * 64 + i * 16 + l4 * 4;
    const int bb = m >> 12;
    const int pos = m & 4095;
#pragma unroll
    for (int j = 0; j < 4; ++j) {
      const int o = wn * 64 + j * 16 + l15;
      *(f32x4*)(out + (((size_t)bb * OCH + o) << 12) + pos) = acc[i][j];
    }
  }
}

extern "C" void kernel_launch(void* const* d_in, const int* in_sizes, int n_in,
                              void* d_out, int out_size, void* d_ws,
                              size_t ws_size, hipStream_t stream) {
  const float* x = (const float*)d_in[0];
  const float* w_off = (const float*)d_in[1];
  const float* b_off = (const float*)d_in[2];
  const float* w_dcn = (const float*)d_in[3];
  float* out = (float*)d_out;

  char* ws = (char*)d_ws;
  float* off_buf = (float*)(ws);                            //  2,359,296 B
  unsigned short* Wop = (unsigned short*)(ws + 2359296);    //    147,456 B
  unsigned short* zp = (unsigned short*)(ws + 2506752);     //      1,024 B
  unsigned short* W2 = (unsigned short*)(ws + 2507776);     //  1,179,648 B
  unsigned short* xTbf = (unsigned short*)(ws + 3687424);   // 16,777,216 B
  // total 20,464,640 B

  prep<<<2304, 256, 0, stream>>>(w_dcn, w_off, W2, Wop, zp);
  xpose<<<2048, 256, 0, stream>>>(x, xTbf);
  offset_gemm<<<256, 256, 0, stream>>>(xTbf, Wop, zp, b_off, off_buf);
  dcn_fused<<<256, 512, 0, stream>>>(xTbf, off_buf, W2, out);
}